// Round 1
// baseline (134.066 us; speedup 1.0000x reference)
//
#include <hip/hip_runtime.h>
#include <hip/hip_bf16.h>

// Problem: B=4, N=M=2048, C=512, H=8, D=64
#define DIMC 512
#define NB   2048
#define MB   2048
#define ROWS 8192   // B*N = B*M

typedef __attribute__((ext_vector_type(8))) short s8v;
typedef __attribute__((ext_vector_type(4))) short s4v;
typedef __attribute__((ext_vector_type(4))) float f4v;

__device__ __forceinline__ unsigned short cvt_bf16(float x) {
  union { float f; unsigned u; } v; v.f = x;
  unsigned r = v.u + 0x7fffu + ((v.u >> 16) & 1u);
  return (unsigned short)(r >> 16);
}

__device__ __forceinline__ void gload16(const void* g, void* l) {
  __builtin_amdgcn_global_load_lds(
      (const __attribute__((address_space(1))) unsigned int*)g,
      (__attribute__((address_space(3))) unsigned int*)l, 16, 0, 0);
}

// ---------------- LayerNorm + bf16 cast (one wave per 512-elem row) -------
__global__ void ln_kernel(const float* __restrict__ x, const float* __restrict__ ctx,
                          const float* __restrict__ gq, const float* __restrict__ bq,
                          const float* __restrict__ gkv, const float* __restrict__ bkv,
                          unsigned short* __restrict__ xn, unsigned short* __restrict__ cn) {
  int row  = blockIdx.x * 4 + (threadIdx.x >> 6);
  int lane = threadIdx.x & 63;
  const float* src; unsigned short* dst; const float* g; const float* b;
  if (row < ROWS) { src = x   + (size_t)row * DIMC;        dst = xn + (size_t)row * DIMC;        g = gq;  b = bq;  }
  else            { src = ctx + (size_t)(row-ROWS) * DIMC; dst = cn + (size_t)(row-ROWS) * DIMC; g = gkv; b = bkv; }

  float4 v0 = ((const float4*)src)[lane];
  float4 v1 = ((const float4*)src)[lane + 64];
  float s  = v0.x+v0.y+v0.z+v0.w + v1.x+v1.y+v1.z+v1.w;
  float ss = v0.x*v0.x+v0.y*v0.y+v0.z*v0.z+v0.w*v0.w
           + v1.x*v1.x+v1.y*v1.y+v1.z*v1.z+v1.w*v1.w;
  #pragma unroll
  for (int m = 1; m <= 32; m <<= 1) { s += __shfl_xor(s, m); ss += __shfl_xor(ss, m); }
  float mu  = s * (1.0f/512.0f);
  float var = ss * (1.0f/512.0f) - mu*mu;
  float rs  = rsqrtf(var + 1e-5f);

  int i0 = lane*4, i1 = 256 + lane*4;
  ushort4 o0, o1;
  o0.x = cvt_bf16((v0.x-mu)*rs*g[i0+0] + b[i0+0]);
  o0.y = cvt_bf16((v0.y-mu)*rs*g[i0+1] + b[i0+1]);
  o0.z = cvt_bf16((v0.z-mu)*rs*g[i0+2] + b[i0+2]);
  o0.w = cvt_bf16((v0.w-mu)*rs*g[i0+3] + b[i0+3]);
  o1.x = cvt_bf16((v1.x-mu)*rs*g[i1+0] + b[i1+0]);
  o1.y = cvt_bf16((v1.y-mu)*rs*g[i1+1] + b[i1+1]);
  o1.z = cvt_bf16((v1.z-mu)*rs*g[i1+2] + b[i1+2]);
  o1.w = cvt_bf16((v1.w-mu)*rs*g[i1+3] + b[i1+3]);
  *(ushort4*)&dst[i0] = o0;
  *(ushort4*)&dst[i1] = o1;
}

// ---------------- Weight transpose + bf16 cast: Wt[n][k] = W[k][n] --------
__global__ void wt_kernel(const float* __restrict__ Wq, const float* __restrict__ Wk,
                          const float* __restrict__ Wv, const float* __restrict__ Wo,
                          unsigned short* __restrict__ Wt) {
  __shared__ float tile[64][65];
  int z = blockIdx.z;
  const float* W = (z==0) ? Wq : (z==1) ? Wk : (z==2) ? Wv : Wo;
  unsigned short* dst = Wt + (size_t)z * DIMC * DIMC;
  int k0 = blockIdx.x * 64, n0 = blockIdx.y * 64;
  int tid = threadIdx.x;
  #pragma unroll
  for (int i = 0; i < 16; ++i) {
    int idx = tid + i*256; int r = idx >> 6, c = idx & 63;
    tile[r][c] = W[(size_t)(k0+r)*DIMC + n0 + c];
  }
  __syncthreads();
  #pragma unroll
  for (int i = 0; i < 16; ++i) {
    int idx = tid + i*256; int r = idx >> 6, c = idx & 63;
    dst[(size_t)(n0+r)*DIMC + k0 + c] = cvt_bf16(tile[c][r]);
  }
}

// ---------------- QKV projection GEMM: C = A @ W + bias, bf16 out --------
// A: [8192][512] bf16, B = W^T: [512][512] bf16 (row n holds W[:,n])
__global__ void gemm_qkv(const unsigned short* __restrict__ xn, const unsigned short* __restrict__ cnr,
                         const unsigned short* __restrict__ Wt,
                         const float* __restrict__ bq, const float* __restrict__ bk, const float* __restrict__ bv,
                         unsigned short* __restrict__ Qo, unsigned short* __restrict__ Ko,
                         unsigned short* __restrict__ Vo) {
  int z = blockIdx.z;
  const unsigned short* A = (z == 0) ? xn : cnr;
  const unsigned short* B = Wt + (size_t)z * DIMC * DIMC;
  const float* bias       = (z==0) ? bq : (z==1) ? bk : bv;
  unsigned short* C       = (z==0) ? Qo : (z==1) ? Ko : Vo;

  __shared__ unsigned short As[128][64];
  __shared__ unsigned short Bs[128][64];

  int tid = threadIdx.x;
  int w = tid >> 6, lane = tid & 63;
  int wr = w >> 1, wc = w & 1;
  int mBase = blockIdx.x * 128, nBase = blockIdx.y * 128;

  f4v zf = {0.f, 0.f, 0.f, 0.f};
  f4v acc[4][4];
  #pragma unroll
  for (int m = 0; m < 4; ++m)
    #pragma unroll
    for (int n = 0; n < 4; ++n) acc[m][n] = zf;

  const unsigned short* gA = A + (size_t)(mBase + (lane>>3)) * DIMC + (lane&7)*8;
  const unsigned short* gB = B + (size_t)(nBase + (lane>>3)) * DIMC + (lane&7)*8;

  for (int kt = 0; kt < 8; ++kt) {
    int k0 = kt * 64;
    if (kt) __syncthreads();
    #pragma unroll
    for (int r = 0; r < 4; ++r) {
      int row0 = r*32 + w*8;
      gload16(gA + (size_t)row0 * DIMC + k0, &As[row0][0]);
      gload16(gB + (size_t)row0 * DIMC + k0, &Bs[row0][0]);
    }
    __syncthreads();
    #pragma unroll
    for (int t = 0; t < 2; ++t) {
      s8v af[4], bfr[4];
      #pragma unroll
      for (int m = 0; m < 4; ++m)
        af[m] = *(const s8v*)&As[wr*64 + m*16 + (lane&15)][t*32 + (lane>>4)*8];
      #pragma unroll
      for (int n = 0; n < 4; ++n)
        bfr[n] = *(const s8v*)&Bs[wc*64 + n*16 + (lane&15)][t*32 + (lane>>4)*8];
      #pragma unroll
      for (int m = 0; m < 4; ++m)
        #pragma unroll
        for (int n = 0; n < 4; ++n)
          acc[m][n] = __builtin_amdgcn_mfma_f32_16x16x32_bf16(af[m], bfr[n], acc[m][n], 0, 0, 0);
    }
  }

  #pragma unroll
  for (int m = 0; m < 4; ++m) {
    int row = mBase + wr*64 + m*16 + (lane>>4)*4;
    #pragma unroll
    for (int n = 0; n < 4; ++n) {
      int col = nBase + wc*64 + n*16 + (lane&15);
      float bb = bias[col];
      #pragma unroll
      for (int j = 0; j < 4; ++j)
        C[(size_t)(row+j)*DIMC + col] = cvt_bf16(acc[m][n][j] + bb);
    }
  }
}

// ---------------- Output GEMM: out = A @ Wo + bo + residual, fp32 out ----
__global__ void gemm_out(const unsigned short* __restrict__ A, const unsigned short* __restrict__ Bt,
                         const float* __restrict__ bo, const float* __restrict__ resid,
                         float* __restrict__ out) {
  __shared__ unsigned short As[128][64];
  __shared__ unsigned short Bs[128][64];

  int tid = threadIdx.x;
  int w = tid >> 6, lane = tid & 63;
  int wr = w >> 1, wc = w & 1;
  int mBase = blockIdx.x * 128, nBase = blockIdx.y * 128;

  f4v zf = {0.f, 0.f, 0.f, 0.f};
  f4v acc[4][4];
  #pragma unroll
  for (int m = 0; m < 4; ++m)
    #pragma unroll
    for (int n = 0; n < 4; ++n) acc[m][n] = zf;

  const unsigned short* gA = A  + (size_t)(mBase + (lane>>3)) * DIMC + (lane&7)*8;
  const unsigned short* gB = Bt + (size_t)(nBase + (lane>>3)) * DIMC + (lane&7)*8;

  for (int kt = 0; kt < 8; ++kt) {
    int k0 = kt * 64;
    if (kt) __syncthreads();
    #pragma unroll
    for (int r = 0; r < 4; ++r) {
      int row0 = r*32 + w*8;
      gload16(gA + (size_t)row0 * DIMC + k0, &As[row0][0]);
      gload16(gB + (size_t)row0 * DIMC + k0, &Bs[row0][0]);
    }
    __syncthreads();
    #pragma unroll
    for (int t = 0; t < 2; ++t) {
      s8v af[4], bfr[4];
      #pragma unroll
      for (int m = 0; m < 4; ++m)
        af[m] = *(const s8v*)&As[wr*64 + m*16 + (lane&15)][t*32 + (lane>>4)*8];
      #pragma unroll
      for (int n = 0; n < 4; ++n)
        bfr[n] = *(const s8v*)&Bs[wc*64 + n*16 + (lane&15)][t*32 + (lane>>4)*8];
      #pragma unroll
      for (int m = 0; m < 4; ++m)
        #pragma unroll
        for (int n = 0; n < 4; ++n)
          acc[m][n] = __builtin_amdgcn_mfma_f32_16x16x32_bf16(af[m], bfr[n], acc[m][n], 0, 0, 0);
    }
  }

  #pragma unroll
  for (int m = 0; m < 4; ++m) {
    int row = mBase + wr*64 + m*16 + (lane>>4)*4;
    #pragma unroll
    for (int n = 0; n < 4; ++n) {
      int col = nBase + wc*64 + n*16 + (lane&15);
      float bb = bo[col];
      #pragma unroll
      for (int j = 0; j < 4; ++j) {
        size_t idx = (size_t)(row+j)*DIMC + col;
        out[idx] = acc[m][n][j] + bb + resid[idx];
      }
    }
  }
}

// ---------------- Flash cross-attention --------------------------------
// Per block: 64 Q rows (4 waves x 16), loop KV in tiles of 64.
// S^T = mfma(A=K_tile, B=Q^T): lane&15 = q-row, so softmax state is per-lane
// and P is repacked in-register (consistent k-permutation on P and V).
__global__ void attn_kernel(const unsigned short* __restrict__ Q, const unsigned short* __restrict__ K,
                            const unsigned short* __restrict__ V, unsigned short* __restrict__ O) {
  __shared__ unsigned short Kt[64][72];  // [key][d], pad 72 for 16B-aligned b128
  __shared__ unsigned short Vt[64][72];  // [d][key] (transposed), pad 72

  int tid = threadIdx.x, w = tid >> 6, lane = tid & 63;
  int qb = blockIdx.x;          // 0..31  (64 q-rows each)
  int bh = blockIdx.y;          // 0..31
  int b = bh >> 3, h = bh & 7;
  size_t base = ((size_t)b * NB) * DIMC + h * 64;

  int g = lane >> 4;            // 0..3
  int l15 = lane & 15;

  // Q fragments (B-operand): col = lane&15 -> qrow, k = g*8+j -> d
  int qrow = qb*64 + w*16 + l15;
  const s8v qf0 = *(const s8v*)&Q[base + (size_t)qrow*DIMC + g*8];
  const s8v qf1 = *(const s8v*)&Q[base + (size_t)qrow*DIMC + 32 + g*8];

  f4v zf = {0.f, 0.f, 0.f, 0.f};
  f4v o_[4];
  #pragma unroll
  for (int c = 0; c < 4; ++c) o_[c] = zf;
  float m_run = -1e30f, l_run = 0.f;
  const float ksc = 0.125f * 1.44269504f;   // scale * log2(e)

  // staging indices
  int skey = tid >> 3;               // 0..31 (+32 on round 2)
  int sd   = (tid & 7) * 8;
  int kp   = lane & 31;              // key pair
  int vd0  = w*16 + (lane >> 5)*8;   // d base for V transpose staging

  for (int kv = 0; kv < MB; kv += 64) {
    __syncthreads();
    // stage K tile [64][64]
    #pragma unroll
    for (int r = 0; r < 2; ++r) {
      int key = skey + r*32;
      s8v kv8 = *(const s8v*)&K[base + (size_t)(kv + key)*DIMC + sd];
      *(s8v*)&Kt[key][sd] = kv8;
    }
    // stage V transposed: Vt[d][key]
    {
      s8v v0 = *(const s8v*)&V[base + (size_t)(kv + 2*kp    )*DIMC + vd0];
      s8v v1 = *(const s8v*)&V[base + (size_t)(kv + 2*kp + 1)*DIMC + vd0];
      #pragma unroll
      for (int i = 0; i < 8; ++i) {
        ushort2 pr; pr.x = (unsigned short)v0[i]; pr.y = (unsigned short)v1[i];
        *(ushort2*)&Vt[vd0 + i][2*kp] = pr;
      }
    }
    __syncthreads();

    // S^T = K @ Q^T: 4 key-chunks of 16
    f4v st[4];
    #pragma unroll
    for (int c = 0; c < 4; ++c) {
      s8v ka = *(const s8v*)&Kt[c*16 + l15][g*8];
      st[c] = __builtin_amdgcn_mfma_f32_16x16x32_bf16(ka, qf0, zf, 0, 0, 0);
      s8v kb = *(const s8v*)&Kt[c*16 + l15][32 + g*8];
      st[c] = __builtin_amdgcn_mfma_f32_16x16x32_bf16(kb, qf1, st[c], 0, 0, 0);
    }

    // online softmax (per-lane row = qrow = lane&15; reduce over 4 lane-groups)
    float mt = -1e30f;
    #pragma unroll
    for (int c = 0; c < 4; ++c)
      #pragma unroll
      for (int j = 0; j < 4; ++j) mt = fmaxf(mt, st[c][j]);
    mt = fmaxf(mt, __shfl_xor(mt, 16));
    mt = fmaxf(mt, __shfl_xor(mt, 32));
    float mn = fmaxf(m_run, mt);

    float pt[4][4]; float ps = 0.f;
    #pragma unroll
    for (int c = 0; c < 4; ++c)
      #pragma unroll
      for (int j = 0; j < 4; ++j) {
        float p = __builtin_amdgcn_exp2f((st[c][j] - mn) * ksc);
        pt[c][j] = p; ps += p;
      }
    ps += __shfl_xor(ps, 16); ps += __shfl_xor(ps, 32);
    float f = __builtin_amdgcn_exp2f((m_run - mn) * ksc);
    l_run = l_run * f + ps;
    m_run = mn;

    // rescale O (O rows are (lane>>4)*4+j -> need f of that q-row)
    float fb[4];
    #pragma unroll
    for (int j = 0; j < 4; ++j) fb[j] = __shfl(f, g*4 + j);
    #pragma unroll
    for (int c = 0; c < 4; ++c) {
      o_[c][0] *= fb[0]; o_[c][1] *= fb[1]; o_[c][2] *= fb[2]; o_[c][3] *= fb[3];
    }

    // pack P into PV A-fragments (k-slot (g,j') -> key 32t + (j'>>2)*16 + 4g + (j'&3))
    s8v pa0, pa1;
    #pragma unroll
    for (int e = 0; e < 8; ++e) {
      pa0[e] = (short)cvt_bf16(pt[(e >> 2)    ][e & 3]);
      pa1[e] = (short)cvt_bf16(pt[(e >> 2) + 2][e & 3]);
    }

    // PV: O += P @ V, B-frag from Vt with the same key permutation
    #pragma unroll
    for (int c = 0; c < 4; ++c) {
      int d = c*16 + l15;
      s8v vf0, vf1;
      {
        s4v lo = *(const s4v*)&Vt[d][4*g];
        s4v hi = *(const s4v*)&Vt[d][16 + 4*g];
        #pragma unroll
        for (int e = 0; e < 4; ++e) { vf0[e] = lo[e]; vf0[e+4] = hi[e]; }
      }
      {
        s4v lo = *(const s4v*)&Vt[d][32 + 4*g];
        s4v hi = *(const s4v*)&Vt[d][48 + 4*g];
        #pragma unroll
        for (int e = 0; e < 4; ++e) { vf1[e] = lo[e]; vf1[e+4] = hi[e]; }
      }
      o_[c] = __builtin_amdgcn_mfma_f32_16x16x32_bf16(pa0, vf0, o_[c], 0, 0, 0);
      o_[c] = __builtin_amdgcn_mfma_f32_16x16x32_bf16(pa1, vf1, o_[c], 0, 0, 0);
    }
  }

  // finalize: divide by row sum, store bf16
  float lb[4];
  #pragma unroll
  for (int j = 0; j < 4; ++j) lb[j] = 1.0f / __shfl(l_run, g*4 + j);
  int nrow = qb*64 + w*16 + g*4;
  #pragma unroll
  for (int c = 0; c < 4; ++c) {
    int d = h*64 + c*16 + l15;
    #pragma unroll
    for (int j = 0; j < 4; ++j)
      O[((size_t)b*NB + nrow + j) * DIMC + d] = cvt_bf16(o_[c][j] * lb[j]);
  }
}

// ---------------- launch --------------------------------------------------
extern "C" void kernel_launch(void* const* d_in, const int* in_sizes, int n_in,
                              void* d_out, int out_size, void* d_ws, size_t ws_size,
                              hipStream_t stream) {
  const float* x    = (const float*)d_in[0];
  const float* ctx  = (const float*)d_in[1];
  const float* g_q  = (const float*)d_in[2];
  const float* b_q  = (const float*)d_in[3];
  const float* g_kv = (const float*)d_in[4];
  const float* b_kv = (const float*)d_in[5];
  const float* Wq   = (const float*)d_in[6];
  const float* bq   = (const float*)d_in[7];
  const float* Wk   = (const float*)d_in[8];
  const float* bk   = (const float*)d_in[9];
  const float* Wv   = (const float*)d_in[10];
  const float* bv   = (const float*)d_in[11];
  const float* Wo   = (const float*)d_in[12];
  const float* bo   = (const float*)d_in[13];
  float* out = (float*)d_out;

  char* ws = (char*)d_ws;
  unsigned short* xn = (unsigned short*)(ws);                    //  8 MB
  unsigned short* cn = (unsigned short*)(ws + 8388608);          //  8 MB
  unsigned short* Wt = (unsigned short*)(ws + 16777216);         //  2 MB (4 matrices)
  unsigned short* Qb = (unsigned short*)(ws + 18874368);         //  8 MB
  unsigned short* Kb = (unsigned short*)(ws + 27262976);         //  8 MB
  unsigned short* Vb = (unsigned short*)(ws + 35651584);         //  8 MB
  unsigned short* Ab = cn;  // attention output reuses cn (dead after QKV GEMM)

  ln_kernel<<<4096, 256, 0, stream>>>(x, ctx, g_q, b_q, g_kv, b_kv, xn, cn);
  wt_kernel<<<dim3(8, 8, 4), 256, 0, stream>>>(Wq, Wk, Wv, Wo, Wt);
  gemm_qkv<<<dim3(64, 4, 3), 256, 0, stream>>>(xn, cn, Wt, bq, bk, bv, Qb, Kb, Vb);
  attn_kernel<<<dim3(32, 32), 256, 0, stream>>>(Qb, Kb, Vb, Ab);
  gemm_out<<<dim3(64, 4), 256, 0, stream>>>(Ab, Wt + 3*DIMC*DIMC, bo, x, out);
}

// Round 3
// 129.474 us; speedup vs baseline: 1.0355x; 1.0355x over previous
//
#include <hip/hip_runtime.h>
#include <hip/hip_bf16.h>

// Problem: B=4, N=M=2048, C=512, H=8, D=64
#define DIMC 512
#define NB   2048
#define MB   2048
#define ROWS 8192   // B*N = B*M
#define KVB  128

typedef __attribute__((ext_vector_type(8))) short s8v;
typedef __attribute__((ext_vector_type(4))) short s4v;
typedef __attribute__((ext_vector_type(4))) float f4v;

__device__ __forceinline__ unsigned short cvt_bf16(float x) {
  union { float f; unsigned u; } v; v.f = x;
  unsigned r = v.u + 0x7fffu + ((v.u >> 16) & 1u);
  return (unsigned short)(r >> 16);
}

__device__ __forceinline__ void gload16(const void* g, void* l) {
  __builtin_amdgcn_global_load_lds(
      (const __attribute__((address_space(1))) unsigned int*)g,
      (__attribute__((address_space(3))) unsigned int*)l, 16, 0, 0);
}

__device__ __forceinline__ unsigned cvt_pk_bf16(float a, float b) {
  unsigned r;
  asm("v_cvt_pk_bf16_f32 %0, %1, %2" : "=v"(r) : "v"(a), "v"(b));
  return r;   // low16 = bf16(a), high16 = bf16(b)
}

// ---------------- LayerNorm + bf16 cast (one wave per 512-elem row) -------
__global__ void ln_kernel(const float* __restrict__ x, const float* __restrict__ ctx,
                          const float* __restrict__ gq, const float* __restrict__ bq,
                          const float* __restrict__ gkv, const float* __restrict__ bkv,
                          unsigned short* __restrict__ xn, unsigned short* __restrict__ cn) {
  int row  = blockIdx.x * 4 + (threadIdx.x >> 6);
  int lane = threadIdx.x & 63;
  const float* src; unsigned short* dst; const float* g; const float* b;
  if (row < ROWS) { src = x   + (size_t)row * DIMC;        dst = xn + (size_t)row * DIMC;        g = gq;  b = bq;  }
  else            { src = ctx + (size_t)(row-ROWS) * DIMC; dst = cn + (size_t)(row-ROWS) * DIMC; g = gkv; b = bkv; }

  float4 v0 = ((const float4*)src)[lane];
  float4 v1 = ((const float4*)src)[lane + 64];
  float s  = v0.x+v0.y+v0.z+v0.w + v1.x+v1.y+v1.z+v1.w;
  float ss = v0.x*v0.x+v0.y*v0.y+v0.z*v0.z+v0.w*v0.w
           + v1.x*v1.x+v1.y*v1.y+v1.z*v1.z+v1.w*v1.w;
  #pragma unroll
  for (int m = 1; m <= 32; m <<= 1) { s += __shfl_xor(s, m); ss += __shfl_xor(ss, m); }
  float mu  = s * (1.0f/512.0f);
  float var = ss * (1.0f/512.0f) - mu*mu;
  float rs  = rsqrtf(var + 1e-5f);

  int i0 = lane*4, i1 = 256 + lane*4;
  ushort4 o0, o1;
  o0.x = cvt_bf16((v0.x-mu)*rs*g[i0+0] + b[i0+0]);
  o0.y = cvt_bf16((v0.y-mu)*rs*g[i0+1] + b[i0+1]);
  o0.z = cvt_bf16((v0.z-mu)*rs*g[i0+2] + b[i0+2]);
  o0.w = cvt_bf16((v0.w-mu)*rs*g[i0+3] + b[i0+3]);
  o1.x = cvt_bf16((v1.x-mu)*rs*g[i1+0] + b[i1+0]);
  o1.y = cvt_bf16((v1.y-mu)*rs*g[i1+1] + b[i1+1]);
  o1.z = cvt_bf16((v1.z-mu)*rs*g[i1+2] + b[i1+2]);
  o1.w = cvt_bf16((v1.w-mu)*rs*g[i1+3] + b[i1+3]);
  *(ushort4*)&dst[i0] = o0;
  *(ushort4*)&dst[i1] = o1;
}

// ---------------- Weight transpose + bf16 cast: Wt[n][k] = W[k][n] --------
__global__ void wt_kernel(const float* __restrict__ Wq, const float* __restrict__ Wk,
                          const float* __restrict__ Wv, const float* __restrict__ Wo,
                          unsigned short* __restrict__ Wt) {
  __shared__ float tile[64][65];
  int z = blockIdx.z;
  const float* W = (z==0) ? Wq : (z==1) ? Wk : (z==2) ? Wv : Wo;
  unsigned short* dst = Wt + (size_t)z * DIMC * DIMC;
  int k0 = blockIdx.x * 64, n0 = blockIdx.y * 64;
  int tid = threadIdx.x;
  #pragma unroll
  for (int i = 0; i < 16; ++i) {
    int idx = tid + i*256; int r = idx >> 6, c = idx & 63;
    tile[r][c] = W[(size_t)(k0+r)*DIMC + n0 + c];
  }
  __syncthreads();
  #pragma unroll
  for (int i = 0; i < 16; ++i) {
    int idx = tid + i*256; int r = idx >> 6, c = idx & 63;
    dst[(size_t)(n0+r)*DIMC + k0 + c] = cvt_bf16(tile[c][r]);
  }
}

// ---------------- QKV projection GEMM: C = (A @ W + bias) * cs, bf16 out --
// Q (z==0) pre-scaled by D^-0.5 * log2(e) so attn softmax uses exp2 direct.
__global__ void gemm_qkv(const unsigned short* __restrict__ xn, const unsigned short* __restrict__ cnr,
                         const unsigned short* __restrict__ Wt,
                         const float* __restrict__ bq, const float* __restrict__ bk, const float* __restrict__ bv,
                         unsigned short* __restrict__ Qo, unsigned short* __restrict__ Ko,
                         unsigned short* __restrict__ Vo) {
  int z = blockIdx.z;
  const unsigned short* A = (z == 0) ? xn : cnr;
  const unsigned short* B = Wt + (size_t)z * DIMC * DIMC;
  const float* bias       = (z==0) ? bq : (z==1) ? bk : bv;
  unsigned short* C       = (z==0) ? Qo : (z==1) ? Ko : Vo;
  const float cs          = (z==0) ? 0.18033688011f : 1.0f;  // (1/8)*log2(e)

  __shared__ unsigned short As[128][64];
  __shared__ unsigned short Bs[128][64];

  int tid = threadIdx.x;
  int w = tid >> 6, lane = tid & 63;
  int wr = w >> 1, wc = w & 1;
  int mBase = blockIdx.x * 128, nBase = blockIdx.y * 128;

  f4v zf = {0.f, 0.f, 0.f, 0.f};
  f4v acc[4][4];
  #pragma unroll
  for (int m = 0; m < 4; ++m)
    #pragma unroll
    for (int n = 0; n < 4; ++n) acc[m][n] = zf;

  const unsigned short* gA = A + (size_t)(mBase + (lane>>3)) * DIMC + (lane&7)*8;
  const unsigned short* gB = B + (size_t)(nBase + (lane>>3)) * DIMC + (lane&7)*8;

  for (int kt = 0; kt < 8; ++kt) {
    int k0 = kt * 64;
    if (kt) __syncthreads();
    #pragma unroll
    for (int r = 0; r < 4; ++r) {
      int row0 = r*32 + w*8;
      gload16(gA + (size_t)row0 * DIMC + k0, &As[row0][0]);
      gload16(gB + (size_t)row0 * DIMC + k0, &Bs[row0][0]);
    }
    __syncthreads();
    #pragma unroll
    for (int t = 0; t < 2; ++t) {
      s8v af[4], bfr[4];
      #pragma unroll
      for (int m = 0; m < 4; ++m)
        af[m] = *(const s8v*)&As[wr*64 + m*16 + (lane&15)][t*32 + (lane>>4)*8];
      #pragma unroll
      for (int n = 0; n < 4; ++n)
        bfr[n] = *(const s8v*)&Bs[wc*64 + n*16 + (lane&15)][t*32 + (lane>>4)*8];
      #pragma unroll
      for (int m = 0; m < 4; ++m)
        #pragma unroll
        for (int n = 0; n < 4; ++n)
          acc[m][n] = __builtin_amdgcn_mfma_f32_16x16x32_bf16(af[m], bfr[n], acc[m][n], 0, 0, 0);
    }
  }

  #pragma unroll
  for (int m = 0; m < 4; ++m) {
    int row = mBase + wr*64 + m*16 + (lane>>4)*4;
    #pragma unroll
    for (int n = 0; n < 4; ++n) {
      int col = nBase + wc*64 + n*16 + (lane&15);
      float bb = bias[col];
      #pragma unroll
      for (int j = 0; j < 4; ++j)
        C[(size_t)(row+j)*DIMC + col] = cvt_bf16((acc[m][n][j] + bb) * cs);
    }
  }
}

// ---------------- Output GEMM: out = A @ Wo + bo + residual, fp32 out ----
__global__ void gemm_out(const unsigned short* __restrict__ A, const unsigned short* __restrict__ Bt,
                         const float* __restrict__ bo, const float* __restrict__ resid,
                         float* __restrict__ out) {
  __shared__ unsigned short As[128][64];
  __shared__ unsigned short Bs[128][64];

  int tid = threadIdx.x;
  int w = tid >> 6, lane = tid & 63;
  int wr = w >> 1, wc = w & 1;
  int mBase = blockIdx.x * 128, nBase = blockIdx.y * 128;

  f4v zf = {0.f, 0.f, 0.f, 0.f};
  f4v acc[4][4];
  #pragma unroll
  for (int m = 0; m < 4; ++m)
    #pragma unroll
    for (int n = 0; n < 4; ++n) acc[m][n] = zf;

  const unsigned short* gA = A  + (size_t)(mBase + (lane>>3)) * DIMC + (lane&7)*8;
  const unsigned short* gB = Bt + (size_t)(nBase + (lane>>3)) * DIMC + (lane&7)*8;

  for (int kt = 0; kt < 8; ++kt) {
    int k0 = kt * 64;
    if (kt) __syncthreads();
    #pragma unroll
    for (int r = 0; r < 4; ++r) {
      int row0 = r*32 + w*8;
      gload16(gA + (size_t)row0 * DIMC + k0, &As[row0][0]);
      gload16(gB + (size_t)row0 * DIMC + k0, &Bs[row0][0]);
    }
    __syncthreads();
    #pragma unroll
    for (int t = 0; t < 2; ++t) {
      s8v af[4], bfr[4];
      #pragma unroll
      for (int m = 0; m < 4; ++m)
        af[m] = *(const s8v*)&As[wr*64 + m*16 + (lane&15)][t*32 + (lane>>4)*8];
      #pragma unroll
      for (int n = 0; n < 4; ++n)
        bfr[n] = *(const s8v*)&Bs[wc*64 + n*16 + (lane&15)][t*32 + (lane>>4)*8];
      #pragma unroll
      for (int m = 0; m < 4; ++m)
        #pragma unroll
        for (int n = 0; n < 4; ++n)
          acc[m][n] = __builtin_amdgcn_mfma_f32_16x16x32_bf16(af[m], bfr[n], acc[m][n], 0, 0, 0);
    }
  }

  #pragma unroll
  for (int m = 0; m < 4; ++m) {
    int row = mBase + wr*64 + m*16 + (lane>>4)*4;
    #pragma unroll
    for (int n = 0; n < 4; ++n) {
      int col = nBase + wc*64 + n*16 + (lane&15);
      float bb = bo[col];
      #pragma unroll
      for (int j = 0; j < 4; ++j) {
        size_t idx = (size_t)(row+j)*DIMC + col;
        out[idx] = acc[m][n][j] + bb + resid[idx];
      }
    }
  }
}

// ---------------- Flash cross-attention --------------------------------
// 64 Q rows per block (4 waves x 16), KV tiles of 128 (2 halves of 64).
// Q pre-scaled by (1/8)*log2e. S^T = mfma(K, Q^T): lane&15 = q-row.
// V staged transposed Vt[d][key] (proven R1 layout), b64 fragment loads.
__global__ void attn_kernel(const unsigned short* __restrict__ Q, const unsigned short* __restrict__ K,
                            const unsigned short* __restrict__ V, unsigned short* __restrict__ O) {
  __shared__ unsigned short Kt[KVB][72];    // [key][d], pad 72 (144B rows, 16B-aligned)
  __shared__ unsigned short Vt[64][136];    // [d][key], pad 136 (272B rows, 8B-aligned cols)

  int tid = threadIdx.x, w = tid >> 6, lane = tid & 63;
  int qb = blockIdx.x;          // 0..31
  int bh = blockIdx.y;          // 0..31
  int b = bh >> 3, h = bh & 7;
  size_t base = ((size_t)b * NB) * DIMC + h * 64;

  int g = lane >> 4;            // 0..3
  int l15 = lane & 15;

  int qrow = qb*64 + w*16 + l15;
  const s8v qf0 = *(const s8v*)&Q[base + (size_t)qrow*DIMC + g*8];
  const s8v qf1 = *(const s8v*)&Q[base + (size_t)qrow*DIMC + 32 + g*8];

  f4v zf = {0.f, 0.f, 0.f, 0.f};
  f4v o_[4];
  #pragma unroll
  for (int c = 0; c < 4; ++c) o_[c] = zf;
  float m_run = -1e30f, l_run = 0.f;

  // K staging indices: 4 rows of 8 d-elems per thread
  int skey = tid >> 3;               // 0..31
  int sd   = (tid & 7) * 8;          // 0..56
  // V transpose staging: 4 keys x 8 d per thread
  int q4  = tid & 31;                // key quad: keys 4*q4 .. 4*q4+3
  int dc8 = (tid >> 5) * 8;          // d base 0..56

  for (int kv = 0; kv < MB; kv += KVB) {
    __syncthreads();
    // stage K tile [128][64]
    #pragma unroll
    for (int r = 0; r < 4; ++r) {
      int key = skey + r*32;
      *(s8v*)&Kt[key][sd] = *(const s8v*)&K[base + (size_t)(kv + key)*DIMC + sd];
    }
    // stage V transposed: Vt[d][key]
    {
      s8v r0 = *(const s8v*)&V[base + (size_t)(kv + 4*q4 + 0)*DIMC + dc8];
      s8v r1 = *(const s8v*)&V[base + (size_t)(kv + 4*q4 + 1)*DIMC + dc8];
      s8v r2 = *(const s8v*)&V[base + (size_t)(kv + 4*q4 + 2)*DIMC + dc8];
      s8v r3 = *(const s8v*)&V[base + (size_t)(kv + 4*q4 + 3)*DIMC + dc8];
      #pragma unroll
      for (int i = 0; i < 8; ++i) {
        ushort4 w4;
        w4.x = (unsigned short)r0[i]; w4.y = (unsigned short)r1[i];
        w4.z = (unsigned short)r2[i]; w4.w = (unsigned short)r3[i];
        *(ushort4*)&Vt[dc8 + i][4*q4] = w4;
      }
    }
    __syncthreads();

    #pragma unroll
    for (int h2 = 0; h2 < 2; ++h2) {
      // QK^T for 64 keys: st[c][j] = S[key=h2*64+16c+4g+j][qrow]
      f4v st[4];
      #pragma unroll
      for (int c = 0; c < 4; ++c) {
        s8v ka = *(const s8v*)&Kt[h2*64 + c*16 + l15][g*8];
        s8v kb = *(const s8v*)&Kt[h2*64 + c*16 + l15][32 + g*8];
        st[c] = __builtin_amdgcn_mfma_f32_16x16x32_bf16(ka, qf0, zf, 0, 0, 0);
        st[c] = __builtin_amdgcn_mfma_f32_16x16x32_bf16(kb, qf1, st[c], 0, 0, 0);
      }

      // hoist V-fragment loads; LDS latency hides under softmax
      s8v vf0[4], vf1[4];
      #pragma unroll
      for (int c = 0; c < 4; ++c) {
        int d = c*16 + l15;
        s4v lo0 = *(const s4v*)&Vt[d][h2*64 +      4*g];
        s4v hi0 = *(const s4v*)&Vt[d][h2*64 + 16 + 4*g];
        s4v lo1 = *(const s4v*)&Vt[d][h2*64 + 32 + 4*g];
        s4v hi1 = *(const s4v*)&Vt[d][h2*64 + 48 + 4*g];
        #pragma unroll
        for (int e = 0; e < 4; ++e) {
          vf0[c][e] = lo0[e]; vf0[c][e+4] = hi0[e];
          vf1[c][e] = lo1[e]; vf1[c][e+4] = hi1[e];
        }
      }

      // row max (per-lane row = l15, reduce across 4 lane-groups)
      float mx0 = fmaxf(fmaxf(st[0][0], st[0][1]), fmaxf(st[0][2], st[0][3]));
      float mx1 = fmaxf(fmaxf(st[1][0], st[1][1]), fmaxf(st[1][2], st[1][3]));
      float mx2 = fmaxf(fmaxf(st[2][0], st[2][1]), fmaxf(st[2][2], st[2][3]));
      float mx3 = fmaxf(fmaxf(st[3][0], st[3][1]), fmaxf(st[3][2], st[3][3]));
      float mt = fmaxf(fmaxf(mx0, mx1), fmaxf(mx2, mx3));
      mt = fmaxf(mt, __shfl_xor(mt, 16));
      mt = fmaxf(mt, __shfl_xor(mt, 32));

      // defer-max: only rescale when max grew by more than 8 (log2 units)
      if (!__all(mt <= m_run + 8.0f)) {
        float mn = fmaxf(m_run, mt);
        float f = __builtin_amdgcn_exp2f(m_run - mn);
        l_run *= f;
        m_run = mn;
        float fb0 = __shfl(f, g*4+0), fb1 = __shfl(f, g*4+1);
        float fb2 = __shfl(f, g*4+2), fb3 = __shfl(f, g*4+3);
        #pragma unroll
        for (int c = 0; c < 4; ++c) {
          o_[c][0] *= fb0; o_[c][1] *= fb1; o_[c][2] *= fb2; o_[c][3] *= fb3;
        }
      }

      float pt[4][4];
      #pragma unroll
      for (int c = 0; c < 4; ++c)
        #pragma unroll
        for (int j = 0; j < 4; ++j)
          pt[c][j] = __builtin_amdgcn_exp2f(st[c][j] - m_run);

      float s0 = (pt[0][0]+pt[0][1]) + (pt[0][2]+pt[0][3]);
      float s1 = (pt[1][0]+pt[1][1]) + (pt[1][2]+pt[1][3]);
      float s2 = (pt[2][0]+pt[2][1]) + (pt[2][2]+pt[2][3]);
      float s3 = (pt[3][0]+pt[3][1]) + (pt[3][2]+pt[3][3]);
      float ps = (s0+s1) + (s2+s3);
      ps += __shfl_xor(ps, 16);
      ps += __shfl_xor(ps, 32);
      l_run += ps;

      // pack P -> bf16 A-fragments (k-slot e -> key (e>>2)*16 + 4g + (e&3))
      union { unsigned i[8]; s8v s[2]; } pu;
      pu.i[0] = cvt_pk_bf16(pt[0][0], pt[0][1]);
      pu.i[1] = cvt_pk_bf16(pt[0][2], pt[0][3]);
      pu.i[2] = cvt_pk_bf16(pt[1][0], pt[1][1]);
      pu.i[3] = cvt_pk_bf16(pt[1][2], pt[1][3]);
      pu.i[4] = cvt_pk_bf16(pt[2][0], pt[2][1]);
      pu.i[5] = cvt_pk_bf16(pt[2][2], pt[2][3]);
      pu.i[6] = cvt_pk_bf16(pt[3][0], pt[3][1]);
      pu.i[7] = cvt_pk_bf16(pt[3][2], pt[3][3]);
      s8v pa0 = pu.s[0], pa1 = pu.s[1];

      #pragma unroll
      for (int c = 0; c < 4; ++c) {
        o_[c] = __builtin_amdgcn_mfma_f32_16x16x32_bf16(pa0, vf0[c], o_[c], 0, 0, 0);
        o_[c] = __builtin_amdgcn_mfma_f32_16x16x32_bf16(pa1, vf1[c], o_[c], 0, 0, 0);
      }
    }
  }

  // finalize: divide by row sum, store bf16
  float lb[4];
  #pragma unroll
  for (int j = 0; j < 4; ++j) lb[j] = 1.0f / __shfl(l_run, g*4 + j);
  int nrow = qb*64 + w*16 + g*4;
  #pragma unroll
  for (int c = 0; c < 4; ++c) {
    int d = h*64 + c*16 + l15;
    #pragma unroll
    for (int j = 0; j < 4; ++j)
      O[((size_t)b*NB + nrow + j) * DIMC + d] = cvt_bf16(o_[c][j] * lb[j]);
  }
}

// ---------------- launch --------------------------------------------------
extern "C" void kernel_launch(void* const* d_in, const int* in_sizes, int n_in,
                              void* d_out, int out_size, void* d_ws, size_t ws_size,
                              hipStream_t stream) {
  const float* x    = (const float*)d_in[0];
  const float* ctx  = (const float*)d_in[1];
  const float* g_q  = (const float*)d_in[2];
  const float* b_q  = (const float*)d_in[3];
  const float* g_kv = (const float*)d_in[4];
  const float* b_kv = (const float*)d_in[5];
  const float* Wq   = (const float*)d_in[6];
  const float* bq   = (const float*)d_in[7];
  const float* Wk   = (const float*)d_in[8];
  const float* bk   = (const float*)d_in[9];
  const float* Wv   = (const float*)d_in[10];
  const float* bv   = (const float*)d_in[11];
  const float* Wo   = (const float*)d_in[12];
  const float* bo   = (const float*)d_in[13];
  float* out = (float*)d_out;

  char* ws = (char*)d_ws;
  unsigned short* xn = (unsigned short*)(ws);                    //  8 MB
  unsigned short* cn = (unsigned short*)(ws + 8388608);          //  8 MB
  unsigned short* Wt = (unsigned short*)(ws + 16777216);         //  2 MB (4 matrices)
  unsigned short* Qb = (unsigned short*)(ws + 18874368);         //  8 MB
  unsigned short* Kb = (unsigned short*)(ws + 27262976);         //  8 MB
  unsigned short* Vb = (unsigned short*)(ws + 35651584);         //  8 MB
  unsigned short* Ab = cn;  // attention output reuses cn (dead after QKV GEMM)

  ln_kernel<<<4096, 256, 0, stream>>>(x, ctx, g_q, b_q, g_kv, b_kv, xn, cn);
  wt_kernel<<<dim3(8, 8, 4), 256, 0, stream>>>(Wq, Wk, Wv, Wo, Wt);
  gemm_qkv<<<dim3(64, 4, 3), 256, 0, stream>>>(xn, cn, Wt, bq, bk, bv, Qb, Kb, Vb);
  attn_kernel<<<dim3(32, 32), 256, 0, stream>>>(Qb, Kb, Vb, Ab);
  gemm_out<<<dim3(64, 4), 256, 0, stream>>>(Ab, Wt + 3*DIMC*DIMC, bo, x, out);
}

// Round 4
// 119.175 us; speedup vs baseline: 1.1249x; 1.0864x over previous
//
#include <hip/hip_runtime.h>
#include <hip/hip_bf16.h>

// Problem: B=4, N=M=2048, C=512, H=8, D=64
#define DIMC 512
#define NB   2048
#define MB   2048
#define ROWS 8192   // B*N = B*M
#define KVB  128

typedef __attribute__((ext_vector_type(8))) short s8v;
typedef __attribute__((ext_vector_type(4))) short s4v;
typedef __attribute__((ext_vector_type(4))) float f4v;

__device__ __forceinline__ unsigned short cvt_bf16(float x) {
  union { float f; unsigned u; } v; v.f = x;
  unsigned r = v.u + 0x7fffu + ((v.u >> 16) & 1u);
  return (unsigned short)(r >> 16);
}

__device__ __forceinline__ void gload16(const void* g, void* l) {
  __builtin_amdgcn_global_load_lds(
      (const __attribute__((address_space(1))) unsigned int*)g,
      (__attribute__((address_space(3))) unsigned int*)l, 16, 0, 0);
}

__device__ __forceinline__ unsigned cvt_pk_bf16(float a, float b) {
  unsigned r;
  asm("v_cvt_pk_bf16_f32 %0, %1, %2" : "=v"(r) : "v"(a), "v"(b));
  return r;   // low16 = bf16(a), high16 = bf16(b)
}

// ---------------- LayerNorm + bf16 cast (one wave per 512-elem row) -------
__global__ void ln_kernel(const float* __restrict__ x, const float* __restrict__ ctx,
                          const float* __restrict__ gq, const float* __restrict__ bq,
                          const float* __restrict__ gkv, const float* __restrict__ bkv,
                          unsigned short* __restrict__ xn, unsigned short* __restrict__ cn) {
  int row  = blockIdx.x * 4 + (threadIdx.x >> 6);
  int lane = threadIdx.x & 63;
  const float* src; unsigned short* dst; const float* g; const float* b;
  if (row < ROWS) { src = x   + (size_t)row * DIMC;        dst = xn + (size_t)row * DIMC;        g = gq;  b = bq;  }
  else            { src = ctx + (size_t)(row-ROWS) * DIMC; dst = cn + (size_t)(row-ROWS) * DIMC; g = gkv; b = bkv; }

  float4 v0 = ((const float4*)src)[lane];
  float4 v1 = ((const float4*)src)[lane + 64];
  float s  = v0.x+v0.y+v0.z+v0.w + v1.x+v1.y+v1.z+v1.w;
  float ss = v0.x*v0.x+v0.y*v0.y+v0.z*v0.z+v0.w*v0.w
           + v1.x*v1.x+v1.y*v1.y+v1.z*v1.z+v1.w*v1.w;
  #pragma unroll
  for (int m = 1; m <= 32; m <<= 1) { s += __shfl_xor(s, m); ss += __shfl_xor(ss, m); }
  float mu  = s * (1.0f/512.0f);
  float var = ss * (1.0f/512.0f) - mu*mu;
  float rs  = rsqrtf(var + 1e-5f);

  int i0 = lane*4, i1 = 256 + lane*4;
  ushort4 o0, o1;
  o0.x = cvt_bf16((v0.x-mu)*rs*g[i0+0] + b[i0+0]);
  o0.y = cvt_bf16((v0.y-mu)*rs*g[i0+1] + b[i0+1]);
  o0.z = cvt_bf16((v0.z-mu)*rs*g[i0+2] + b[i0+2]);
  o0.w = cvt_bf16((v0.w-mu)*rs*g[i0+3] + b[i0+3]);
  o1.x = cvt_bf16((v1.x-mu)*rs*g[i1+0] + b[i1+0]);
  o1.y = cvt_bf16((v1.y-mu)*rs*g[i1+1] + b[i1+1]);
  o1.z = cvt_bf16((v1.z-mu)*rs*g[i1+2] + b[i1+2]);
  o1.w = cvt_bf16((v1.w-mu)*rs*g[i1+3] + b[i1+3]);
  *(ushort4*)&dst[i0] = o0;
  *(ushort4*)&dst[i1] = o1;
}

// ---------------- Weight transpose + bf16 cast: Wt[n][k] = W[k][n] --------
__global__ void wt_kernel(const float* __restrict__ Wq, const float* __restrict__ Wk,
                          const float* __restrict__ Wv, const float* __restrict__ Wo,
                          unsigned short* __restrict__ Wt) {
  __shared__ float tile[64][65];
  int z = blockIdx.z;
  const float* W = (z==0) ? Wq : (z==1) ? Wk : (z==2) ? Wv : Wo;
  unsigned short* dst = Wt + (size_t)z * DIMC * DIMC;
  int k0 = blockIdx.x * 64, n0 = blockIdx.y * 64;
  int tid = threadIdx.x;
  #pragma unroll
  for (int i = 0; i < 16; ++i) {
    int idx = tid + i*256; int r = idx >> 6, c = idx & 63;
    tile[r][c] = W[(size_t)(k0+r)*DIMC + n0 + c];
  }
  __syncthreads();
  #pragma unroll
  for (int i = 0; i < 16; ++i) {
    int idx = tid + i*256; int r = idx >> 6, c = idx & 63;
    dst[(size_t)(n0+r)*DIMC + k0 + c] = cvt_bf16(tile[c][r]);
  }
}

// ---------------- QKV projection GEMM: C = (A @ W + bias) * cs, bf16 out --
// z==0 (Q): pre-scaled by (1/8)*log2e, row-major.
// z==1 (K): row-major. z==2 (V): stored TRANSPOSED as [B][H][64 d][2048 key].
__global__ void gemm_qkv(const unsigned short* __restrict__ xn, const unsigned short* __restrict__ cnr,
                         const unsigned short* __restrict__ Wt,
                         const float* __restrict__ bq, const float* __restrict__ bk, const float* __restrict__ bv,
                         unsigned short* __restrict__ Qo, unsigned short* __restrict__ Ko,
                         unsigned short* __restrict__ Vo) {
  int z = blockIdx.z;
  const unsigned short* A = (z == 0) ? xn : cnr;
  const unsigned short* B = Wt + (size_t)z * DIMC * DIMC;
  const float* bias       = (z==0) ? bq : (z==1) ? bk : bv;
  unsigned short* C       = (z==0) ? Qo : (z==1) ? Ko : Vo;
  const float cs          = (z==0) ? 0.18033688011f : 1.0f;  // (1/8)*log2(e)

  __shared__ unsigned short As[128][64];
  __shared__ unsigned short Bs[128][64];

  int tid = threadIdx.x;
  int w = tid >> 6, lane = tid & 63;
  int wr = w >> 1, wc = w & 1;
  int mBase = blockIdx.x * 128, nBase = blockIdx.y * 128;

  f4v zf = {0.f, 0.f, 0.f, 0.f};
  f4v acc[4][4];
  #pragma unroll
  for (int m = 0; m < 4; ++m)
    #pragma unroll
    for (int n = 0; n < 4; ++n) acc[m][n] = zf;

  const unsigned short* gA = A + (size_t)(mBase + (lane>>3)) * DIMC + (lane&7)*8;
  const unsigned short* gB = B + (size_t)(nBase + (lane>>3)) * DIMC + (lane&7)*8;

  for (int kt = 0; kt < 8; ++kt) {
    int k0 = kt * 64;
    if (kt) __syncthreads();
    #pragma unroll
    for (int r = 0; r < 4; ++r) {
      int row0 = r*32 + w*8;
      gload16(gA + (size_t)row0 * DIMC + k0, &As[row0][0]);
      gload16(gB + (size_t)row0 * DIMC + k0, &Bs[row0][0]);
    }
    __syncthreads();
    #pragma unroll
    for (int t = 0; t < 2; ++t) {
      s8v af[4], bfr[4];
      #pragma unroll
      for (int m = 0; m < 4; ++m)
        af[m] = *(const s8v*)&As[wr*64 + m*16 + (lane&15)][t*32 + (lane>>4)*8];
      #pragma unroll
      for (int n = 0; n < 4; ++n)
        bfr[n] = *(const s8v*)&Bs[wc*64 + n*16 + (lane&15)][t*32 + (lane>>4)*8];
      #pragma unroll
      for (int m = 0; m < 4; ++m)
        #pragma unroll
        for (int n = 0; n < 4; ++n)
          acc[m][n] = __builtin_amdgcn_mfma_f32_16x16x32_bf16(af[m], bfr[n], acc[m][n], 0, 0, 0);
    }
  }

  if (z == 2) {
    // transposed store: V^T[(b*8+h)*64 + d][key], 4 contiguous keys per store
    #pragma unroll
    for (int m = 0; m < 4; ++m) {
      int row = mBase + wr*64 + m*16 + (lane>>4)*4;   // = b*2048 + key
      int b_  = row >> 11, key = row & 2047;
      #pragma unroll
      for (int n = 0; n < 4; ++n) {
        int col = nBase + wc*64 + n*16 + (lane&15);    // = h*64 + d
        float bb = bias[col];
        ushort4 st;
        st.x = cvt_bf16(acc[m][n][0] + bb);
        st.y = cvt_bf16(acc[m][n][1] + bb);
        st.z = cvt_bf16(acc[m][n][2] + bb);
        st.w = cvt_bf16(acc[m][n][3] + bb);
        *(ushort4*)&C[((size_t)(b_*8 + (col>>6))*64 + (col&63))*2048 + key] = st;
      }
    }
  } else {
    #pragma unroll
    for (int m = 0; m < 4; ++m) {
      int row = mBase + wr*64 + m*16 + (lane>>4)*4;
      #pragma unroll
      for (int n = 0; n < 4; ++n) {
        int col = nBase + wc*64 + n*16 + (lane&15);
        float bb = bias[col];
        #pragma unroll
        for (int j = 0; j < 4; ++j)
          C[(size_t)(row+j)*DIMC + col] = cvt_bf16((acc[m][n][j] + bb) * cs);
      }
    }
  }
}

// ---------------- Output GEMM: out = A @ Wo + bo + residual, fp32 out ----
__global__ void gemm_out(const unsigned short* __restrict__ A, const unsigned short* __restrict__ Bt,
                         const float* __restrict__ bo, const float* __restrict__ resid,
                         float* __restrict__ out) {
  __shared__ unsigned short As[128][64];
  __shared__ unsigned short Bs[128][64];

  int tid = threadIdx.x;
  int w = tid >> 6, lane = tid & 63;
  int wr = w >> 1, wc = w & 1;
  int mBase = blockIdx.x * 128, nBase = blockIdx.y * 128;

  f4v zf = {0.f, 0.f, 0.f, 0.f};
  f4v acc[4][4];
  #pragma unroll
  for (int m = 0; m < 4; ++m)
    #pragma unroll
    for (int n = 0; n < 4; ++n) acc[m][n] = zf;

  const unsigned short* gA = A  + (size_t)(mBase + (lane>>3)) * DIMC + (lane&7)*8;
  const unsigned short* gB = Bt + (size_t)(nBase + (lane>>3)) * DIMC + (lane&7)*8;

  for (int kt = 0; kt < 8; ++kt) {
    int k0 = kt * 64;
    if (kt) __syncthreads();
    #pragma unroll
    for (int r = 0; r < 4; ++r) {
      int row0 = r*32 + w*8;
      gload16(gA + (size_t)row0 * DIMC + k0, &As[row0][0]);
      gload16(gB + (size_t)row0 * DIMC + k0, &Bs[row0][0]);
    }
    __syncthreads();
    #pragma unroll
    for (int t = 0; t < 2; ++t) {
      s8v af[4], bfr[4];
      #pragma unroll
      for (int m = 0; m < 4; ++m)
        af[m] = *(const s8v*)&As[wr*64 + m*16 + (lane&15)][t*32 + (lane>>4)*8];
      #pragma unroll
      for (int n = 0; n < 4; ++n)
        bfr[n] = *(const s8v*)&Bs[wc*64 + n*16 + (lane&15)][t*32 + (lane>>4)*8];
      #pragma unroll
      for (int m = 0; m < 4; ++m)
        #pragma unroll
        for (int n = 0; n < 4; ++n)
          acc[m][n] = __builtin_amdgcn_mfma_f32_16x16x32_bf16(af[m], bfr[n], acc[m][n], 0, 0, 0);
    }
  }

  #pragma unroll
  for (int m = 0; m < 4; ++m) {
    int row = mBase + wr*64 + m*16 + (lane>>4)*4;
    #pragma unroll
    for (int n = 0; n < 4; ++n) {
      int col = nBase + wc*64 + n*16 + (lane&15);
      float bb = bo[col];
      #pragma unroll
      for (int j = 0; j < 4; ++j) {
        size_t idx = (size_t)(row+j)*DIMC + col;
        out[idx] = acc[m][n][j] + bb + resid[idx];
      }
    }
  }
}

// ---------------- Flash cross-attention --------------------------------
// 64 Q rows/block (4 waves x 16), KV tiles of 128. Q pre-scaled (1/8)log2e.
// K: row-major global, staged via gload_lds into Ks[128][64] with source-XOR
//    swizzle S(key,d): byte = key*128 + (2d ^ ((key&7)<<4)).
// V: TRANSPOSED global [B][H][64][2048], staged via gload_lds into Vs[64][128]
//    with swizzle T(d,key): byte = d*256 + (2key ^ ((d&7)<<4)).
__global__ void attn_kernel(const unsigned short* __restrict__ Q, const unsigned short* __restrict__ K,
                            const unsigned short* __restrict__ Vt, unsigned short* __restrict__ O) {
  __shared__ __align__(16) unsigned short Ks[KVB*64];   // 16 KB, swizzled
  __shared__ __align__(16) unsigned short Vs[64*KVB];   // 16 KB, swizzled

  int tid = threadIdx.x, w = tid >> 6, lane = tid & 63;
  int qb = blockIdx.x;          // 0..31
  int bh = blockIdx.y;          // 0..31
  int b = bh >> 3, h = bh & 7;
  size_t base  = ((size_t)b * NB) * DIMC + h * 64;        // Q/K row-major base
  size_t vbase = (size_t)(b*8 + h) * 64 * 2048;           // V^T base

  int g = lane >> 4;            // 0..3
  int l15 = lane & 15;

  int qrow = qb*64 + w*16 + l15;
  const s8v qf0 = *(const s8v*)&Q[base + (size_t)qrow*DIMC + g*8];
  const s8v qf1 = *(const s8v*)&Q[base + (size_t)qrow*DIMC + 32 + g*8];

  f4v zf = {0.f, 0.f, 0.f, 0.f};
  f4v o_[4];
  #pragma unroll
  for (int c = 0; c < 4; ++c) o_[c] = zf;
  float m_run = -1e30f, l_run = 0.f;

  // staging address components (per thread)
  int kkey_l = lane >> 3;                      // 0..7   key sub-index (K)
  int kd0    = ((lane & 7) ^ (lane >> 3)) * 8; // d start (K source swizzle)
  int vd_l   = lane >> 4;                      // 0..3   d sub-index (V)

  for (int kv = 0; kv < MB; kv += KVB) {
    __syncthreads();
    // stage K: wave w covers keys w*32 .. w*32+31
    #pragma unroll
    for (int r = 0; r < 4; ++r) {
      int key = w*32 + r*8 + kkey_l;
      gload16(K + base + (size_t)(kv + key)*DIMC + kd0,
              (char*)Ks + w*4096 + r*1024);
    }
    // stage V^T: wave w covers d = w*16 .. w*16+15
    #pragma unroll
    for (int r = 0; r < 4; ++r) {
      int d = w*16 + r*4 + vd_l;
      int key0 = ((lane & 15) ^ (d & 7)) * 8;
      gload16(Vt + vbase + (size_t)d*2048 + kv + key0,
              (char*)Vs + w*4096 + r*1024);
    }
    __syncthreads();   // drains vmcnt before any wave reads LDS

    #pragma unroll
    for (int h2 = 0; h2 < 2; ++h2) {
      // QK^T for 64 keys: st[c][j] = S[key=h2*64+16c+4g+j][qrow]
      f4v st[4];
      #pragma unroll
      for (int c = 0; c < 4; ++c) {
        int key = h2*64 + c*16 + l15;
        const unsigned short* kr = Ks + key*64;
        int sw = (key & 7) << 4;
        s8v ka = *(const s8v*)(kr + (((g*16      ) ^ sw) >> 1));
        s8v kb = *(const s8v*)(kr + (((64 + g*16 ) ^ sw) >> 1));
        st[c] = __builtin_amdgcn_mfma_f32_16x16x32_bf16(ka, qf0, zf, 0, 0, 0);
        st[c] = __builtin_amdgcn_mfma_f32_16x16x32_bf16(kb, qf1, st[c], 0, 0, 0);
      }

      // hoist V-fragment loads; LDS latency hides under softmax
      s8v vf0[4], vf1[4];
      #pragma unroll
      for (int c = 0; c < 4; ++c) {
        int d = c*16 + l15;
        const unsigned short* vr = Vs + d*128;
        int sw = (d & 7) << 4;
        s4v lo0 = *(const s4v*)(vr + (((h2*128      + g*8) ^ sw) >> 1));
        s4v hi0 = *(const s4v*)(vr + (((h2*128 + 32 + g*8) ^ sw) >> 1));
        s4v lo1 = *(const s4v*)(vr + (((h2*128 + 64 + g*8) ^ sw) >> 1));
        s4v hi1 = *(const s4v*)(vr + (((h2*128 + 96 + g*8) ^ sw) >> 1));
        #pragma unroll
        for (int e = 0; e < 4; ++e) {
          vf0[c][e] = lo0[e]; vf0[c][e+4] = hi0[e];
          vf1[c][e] = lo1[e]; vf1[c][e+4] = hi1[e];
        }
      }

      // row max (per-lane row = l15, reduce across 4 lane-groups)
      float mx0 = fmaxf(fmaxf(st[0][0], st[0][1]), fmaxf(st[0][2], st[0][3]));
      float mx1 = fmaxf(fmaxf(st[1][0], st[1][1]), fmaxf(st[1][2], st[1][3]));
      float mx2 = fmaxf(fmaxf(st[2][0], st[2][1]), fmaxf(st[2][2], st[2][3]));
      float mx3 = fmaxf(fmaxf(st[3][0], st[3][1]), fmaxf(st[3][2], st[3][3]));
      float mt = fmaxf(fmaxf(mx0, mx1), fmaxf(mx2, mx3));
      mt = fmaxf(mt, __shfl_xor(mt, 16));
      mt = fmaxf(mt, __shfl_xor(mt, 32));

      // defer-max: only rescale when max grew by more than 8 (log2 units)
      if (!__all(mt <= m_run + 8.0f)) {
        float mn = fmaxf(m_run, mt);
        float f = __builtin_amdgcn_exp2f(m_run - mn);
        l_run *= f;
        m_run = mn;
        float fb0 = __shfl(f, g*4+0), fb1 = __shfl(f, g*4+1);
        float fb2 = __shfl(f, g*4+2), fb3 = __shfl(f, g*4+3);
        #pragma unroll
        for (int c = 0; c < 4; ++c) {
          o_[c][0] *= fb0; o_[c][1] *= fb1; o_[c][2] *= fb2; o_[c][3] *= fb3;
        }
      }

      float pt[4][4];
      #pragma unroll
      for (int c = 0; c < 4; ++c)
        #pragma unroll
        for (int j = 0; j < 4; ++j)
          pt[c][j] = __builtin_amdgcn_exp2f(st[c][j] - m_run);

      float s0 = (pt[0][0]+pt[0][1]) + (pt[0][2]+pt[0][3]);
      float s1 = (pt[1][0]+pt[1][1]) + (pt[1][2]+pt[1][3]);
      float s2 = (pt[2][0]+pt[2][1]) + (pt[2][2]+pt[2][3]);
      float s3 = (pt[3][0]+pt[3][1]) + (pt[3][2]+pt[3][3]);
      float ps = (s0+s1) + (s2+s3);
      ps += __shfl_xor(ps, 16);
      ps += __shfl_xor(ps, 32);
      l_run += ps;

      // pack P -> bf16 A-fragments (k-slot e -> key (e>>2)*16 + 4g + (e&3))
      union { unsigned i[8]; s8v s[2]; } pu;
      pu.i[0] = cvt_pk_bf16(pt[0][0], pt[0][1]);
      pu.i[1] = cvt_pk_bf16(pt[0][2], pt[0][3]);
      pu.i[2] = cvt_pk_bf16(pt[1][0], pt[1][1]);
      pu.i[3] = cvt_pk_bf16(pt[1][2], pt[1][3]);
      pu.i[4] = cvt_pk_bf16(pt[2][0], pt[2][1]);
      pu.i[5] = cvt_pk_bf16(pt[2][2], pt[2][3]);
      pu.i[6] = cvt_pk_bf16(pt[3][0], pt[3][1]);
      pu.i[7] = cvt_pk_bf16(pt[3][2], pt[3][3]);
      s8v pa0 = pu.s[0], pa1 = pu.s[1];

      #pragma unroll
      for (int c = 0; c < 4; ++c) {
        o_[c] = __builtin_amdgcn_mfma_f32_16x16x32_bf16(pa0, vf0[c], o_[c], 0, 0, 0);
        o_[c] = __builtin_amdgcn_mfma_f32_16x16x32_bf16(pa1, vf1[c], o_[c], 0, 0, 0);
      }
    }
  }

  // finalize: divide by row sum, store bf16
  float lb[4];
  #pragma unroll
  for (int j = 0; j < 4; ++j) lb[j] = 1.0f / __shfl(l_run, g*4 + j);
  int nrow = qb*64 + w*16 + g*4;
  #pragma unroll
  for (int c = 0; c < 4; ++c) {
    int d = h*64 + c*16 + l15;
    #pragma unroll
    for (int j = 0; j < 4; ++j)
      O[((size_t)b*NB + nrow + j) * DIMC + d] = cvt_bf16(o_[c][j] * lb[j]);
  }
}

// ---------------- launch --------------------------------------------------
extern "C" void kernel_launch(void* const* d_in, const int* in_sizes, int n_in,
                              void* d_out, int out_size, void* d_ws, size_t ws_size,
                              hipStream_t stream) {
  const float* x    = (const float*)d_in[0];
  const float* ctx  = (const float*)d_in[1];
  const float* g_q  = (const float*)d_in[2];
  const float* b_q  = (const float*)d_in[3];
  const float* g_kv = (const float*)d_in[4];
  const float* b_kv = (const float*)d_in[5];
  const float* Wq   = (const float*)d_in[6];
  const float* bq   = (const float*)d_in[7];
  const float* Wk   = (const float*)d_in[8];
  const float* bk   = (const float*)d_in[9];
  const float* Wv   = (const float*)d_in[10];
  const float* bv   = (const float*)d_in[11];
  const float* Wo   = (const float*)d_in[12];
  const float* bo   = (const float*)d_in[13];
  float* out = (float*)d_out;

  char* ws = (char*)d_ws;
  unsigned short* xn = (unsigned short*)(ws);                    //  8 MB
  unsigned short* cn = (unsigned short*)(ws + 8388608);          //  8 MB
  unsigned short* Wt = (unsigned short*)(ws + 16777216);         //  2 MB (4 matrices)
  unsigned short* Qb = (unsigned short*)(ws + 18874368);         //  8 MB
  unsigned short* Kb = (unsigned short*)(ws + 27262976);         //  8 MB
  unsigned short* Vb = (unsigned short*)(ws + 35651584);         //  8 MB (V^T)
  unsigned short* Ab = cn;  // attention output reuses cn (dead after QKV GEMM)

  ln_kernel<<<4096, 256, 0, stream>>>(x, ctx, g_q, b_q, g_kv, b_kv, xn, cn);
  wt_kernel<<<dim3(8, 8, 4), 256, 0, stream>>>(Wq, Wk, Wv, Wo, Wt);
  gemm_qkv<<<dim3(64, 4, 3), 256, 0, stream>>>(xn, cn, Wt, bq, bk, bv, Qb, Kb, Vb);
  attn_kernel<<<dim3(32, 32), 256, 0, stream>>>(Qb, Kb, Vb, Ab);
  gemm_out<<<dim3(64, 4), 256, 0, stream>>>(Ab, Wt + 3*DIMC*DIMC, bo, x, out);
}

// Round 5
// 110.846 us; speedup vs baseline: 1.2095x; 1.0751x over previous
//
#include <hip/hip_runtime.h>
#include <hip/hip_bf16.h>

// Problem: B=4, N=M=2048, C=512, H=8, D=64
#define DIMC 512
#define NB   2048
#define MB   2048
#define ROWS 8192   // B*N = B*M

typedef __attribute__((ext_vector_type(8))) short s8v;
typedef __attribute__((ext_vector_type(4))) short s4v;
typedef __attribute__((ext_vector_type(4))) float f4v;

__device__ __forceinline__ unsigned short cvt_bf16(float x) {
  union { float f; unsigned u; } v; v.f = x;
  unsigned r = v.u + 0x7fffu + ((v.u >> 16) & 1u);
  return (unsigned short)(r >> 16);
}

__device__ __forceinline__ void gload16(const void* g, void* l) {
  __builtin_amdgcn_global_load_lds(
      (const __attribute__((address_space(1))) unsigned int*)g,
      (__attribute__((address_space(3))) unsigned int*)l, 16, 0, 0);
}

__device__ __forceinline__ unsigned cvt_pk_bf16(float a, float b) {
  unsigned r;
  asm("v_cvt_pk_bf16_f32 %0, %1, %2" : "=v"(r) : "v"(a), "v"(b));
  return r;   // low16 = bf16(a), high16 = bf16(b)
}

// ---------------- LayerNorm + bf16 cast (one wave per 512-elem row) -------
__global__ void ln_kernel(const float* __restrict__ x, const float* __restrict__ ctx,
                          const float* __restrict__ gq, const float* __restrict__ bq,
                          const float* __restrict__ gkv, const float* __restrict__ bkv,
                          unsigned short* __restrict__ xn, unsigned short* __restrict__ cn) {
  int row  = blockIdx.x * 4 + (threadIdx.x >> 6);
  int lane = threadIdx.x & 63;
  const float* src; unsigned short* dst; const float* g; const float* b;
  if (row < ROWS) { src = x   + (size_t)row * DIMC;        dst = xn + (size_t)row * DIMC;        g = gq;  b = bq;  }
  else            { src = ctx + (size_t)(row-ROWS) * DIMC; dst = cn + (size_t)(row-ROWS) * DIMC; g = gkv; b = bkv; }

  float4 v0 = ((const float4*)src)[lane];
  float4 v1 = ((const float4*)src)[lane + 64];
  float s  = v0.x+v0.y+v0.z+v0.w + v1.x+v1.y+v1.z+v1.w;
  float ss = v0.x*v0.x+v0.y*v0.y+v0.z*v0.z+v0.w*v0.w
           + v1.x*v1.x+v1.y*v1.y+v1.z*v1.z+v1.w*v1.w;
  #pragma unroll
  for (int m = 1; m <= 32; m <<= 1) { s += __shfl_xor(s, m); ss += __shfl_xor(ss, m); }
  float mu  = s * (1.0f/512.0f);
  float var = ss * (1.0f/512.0f) - mu*mu;
  float rs  = rsqrtf(var + 1e-5f);

  int i0 = lane*4, i1 = 256 + lane*4;
  ushort4 o0, o1;
  o0.x = cvt_bf16((v0.x-mu)*rs*g[i0+0] + b[i0+0]);
  o0.y = cvt_bf16((v0.y-mu)*rs*g[i0+1] + b[i0+1]);
  o0.z = cvt_bf16((v0.z-mu)*rs*g[i0+2] + b[i0+2]);
  o0.w = cvt_bf16((v0.w-mu)*rs*g[i0+3] + b[i0+3]);
  o1.x = cvt_bf16((v1.x-mu)*rs*g[i1+0] + b[i1+0]);
  o1.y = cvt_bf16((v1.y-mu)*rs*g[i1+1] + b[i1+1]);
  o1.z = cvt_bf16((v1.z-mu)*rs*g[i1+2] + b[i1+2]);
  o1.w = cvt_bf16((v1.w-mu)*rs*g[i1+3] + b[i1+3]);
  *(ushort4*)&dst[i0] = o0;
  *(ushort4*)&dst[i1] = o1;
}

// ---------------- Weight transpose + bf16 cast: Wt[n][k] = W[k][n] --------
__global__ void wt_kernel(const float* __restrict__ Wq, const float* __restrict__ Wk,
                          const float* __restrict__ Wv, const float* __restrict__ Wo,
                          unsigned short* __restrict__ Wt) {
  __shared__ float tile[64][65];
  int z = blockIdx.z;
  const float* W = (z==0) ? Wq : (z==1) ? Wk : (z==2) ? Wv : Wo;
  unsigned short* dst = Wt + (size_t)z * DIMC * DIMC;
  int k0 = blockIdx.x * 64, n0 = blockIdx.y * 64;
  int tid = threadIdx.x;
  #pragma unroll
  for (int i = 0; i < 16; ++i) {
    int idx = tid + i*256; int r = idx >> 6, c = idx & 63;
    tile[r][c] = W[(size_t)(k0+r)*DIMC + n0 + c];
  }
  __syncthreads();
  #pragma unroll
  for (int i = 0; i < 16; ++i) {
    int idx = tid + i*256; int r = idx >> 6, c = idx & 63;
    dst[(size_t)(n0+r)*DIMC + k0 + c] = cvt_bf16(tile[c][r]);
  }
}

// ---------------- QKV projection GEMM: C = (A @ W + bias) * cs, bf16 out --
// z==0 (Q): pre-scaled by (1/8)*log2e, row-major.
// z==1 (K): row-major.
// z==2 (V): TRANSPOSED [B][H][64 d][2048], keys PERMUTED within 32-blocks:
//           key=4k+j -> pos = j + ((k>>2)&1)*4 + (k&3)*8 + (k>>3)*32
//           so attn's PV B-fragment is one contiguous b128 in LDS.
__global__ void gemm_qkv(const unsigned short* __restrict__ xn, const unsigned short* __restrict__ cnr,
                         const unsigned short* __restrict__ Wt,
                         const float* __restrict__ bq, const float* __restrict__ bk, const float* __restrict__ bv,
                         unsigned short* __restrict__ Qo, unsigned short* __restrict__ Ko,
                         unsigned short* __restrict__ Vo) {
  int z = blockIdx.z;
  const unsigned short* A = (z == 0) ? xn : cnr;
  const unsigned short* B = Wt + (size_t)z * DIMC * DIMC;
  const float* bias       = (z==0) ? bq : (z==1) ? bk : bv;
  unsigned short* C       = (z==0) ? Qo : (z==1) ? Ko : Vo;
  const float cs          = (z==0) ? 0.18033688011f : 1.0f;  // (1/8)*log2(e)

  __shared__ unsigned short As[128][64];
  __shared__ unsigned short Bs[128][64];

  int tid = threadIdx.x;
  int w = tid >> 6, lane = tid & 63;
  int wr = w >> 1, wc = w & 1;
  int mBase = blockIdx.x * 128, nBase = blockIdx.y * 128;

  f4v zf = {0.f, 0.f, 0.f, 0.f};
  f4v acc[4][4];
  #pragma unroll
  for (int m = 0; m < 4; ++m)
    #pragma unroll
    for (int n = 0; n < 4; ++n) acc[m][n] = zf;

  const unsigned short* gA = A + (size_t)(mBase + (lane>>3)) * DIMC + (lane&7)*8;
  const unsigned short* gB = B + (size_t)(nBase + (lane>>3)) * DIMC + (lane&7)*8;

  for (int kt = 0; kt < 8; ++kt) {
    int k0 = kt * 64;
    if (kt) __syncthreads();
    #pragma unroll
    for (int r = 0; r < 4; ++r) {
      int row0 = r*32 + w*8;
      gload16(gA + (size_t)row0 * DIMC + k0, &As[row0][0]);
      gload16(gB + (size_t)row0 * DIMC + k0, &Bs[row0][0]);
    }
    __syncthreads();
    #pragma unroll
    for (int t = 0; t < 2; ++t) {
      s8v af[4], bfr[4];
      #pragma unroll
      for (int m = 0; m < 4; ++m)
        af[m] = *(const s8v*)&As[wr*64 + m*16 + (lane&15)][t*32 + (lane>>4)*8];
      #pragma unroll
      for (int n = 0; n < 4; ++n)
        bfr[n] = *(const s8v*)&Bs[wc*64 + n*16 + (lane&15)][t*32 + (lane>>4)*8];
      #pragma unroll
      for (int m = 0; m < 4; ++m)
        #pragma unroll
        for (int n = 0; n < 4; ++n)
          acc[m][n] = __builtin_amdgcn_mfma_f32_16x16x32_bf16(af[m], bfr[n], acc[m][n], 0, 0, 0);
    }
  }

  if (z == 2) {
    #pragma unroll
    for (int m = 0; m < 4; ++m) {
      int row = mBase + wr*64 + m*16 + (lane>>4)*4;   // = b*2048 + key (key%4==0)
      int b_  = row >> 11, key = row & 2047;
      int k   = key >> 2;
      int P0  = (((k>>2)&1)<<2) + ((k&3)<<3) + ((k>>3)<<5);
      #pragma unroll
      for (int n = 0; n < 4; ++n) {
        int col = nBase + wc*64 + n*16 + (lane&15);    // = h*64 + d
        float bb = bias[col];
        ushort4 st;
        st.x = cvt_bf16(acc[m][n][0] + bb);
        st.y = cvt_bf16(acc[m][n][1] + bb);
        st.z = cvt_bf16(acc[m][n][2] + bb);
        st.w = cvt_bf16(acc[m][n][3] + bb);
        *(ushort4*)&C[((size_t)(b_*8 + (col>>6))*64 + (col&63))*2048 + P0] = st;
      }
    }
  } else {
    #pragma unroll
    for (int m = 0; m < 4; ++m) {
      int row = mBase + wr*64 + m*16 + (lane>>4)*4;
      #pragma unroll
      for (int n = 0; n < 4; ++n) {
        int col = nBase + wc*64 + n*16 + (lane&15);
        float bb = bias[col];
        #pragma unroll
        for (int j = 0; j < 4; ++j)
          C[(size_t)(row+j)*DIMC + col] = cvt_bf16((acc[m][n][j] + bb) * cs);
      }
    }
  }
}

// ---------------- Output GEMM: out = A @ Wo + bo + residual, fp32 out ----
__global__ void gemm_out(const unsigned short* __restrict__ A, const unsigned short* __restrict__ Bt,
                         const float* __restrict__ bo, const float* __restrict__ resid,
                         float* __restrict__ out) {
  __shared__ unsigned short As[128][64];
  __shared__ unsigned short Bs[128][64];

  int tid = threadIdx.x;
  int w = tid >> 6, lane = tid & 63;
  int wr = w >> 1, wc = w & 1;
  int mBase = blockIdx.x * 128, nBase = blockIdx.y * 128;

  f4v zf = {0.f, 0.f, 0.f, 0.f};
  f4v acc[4][4];
  #pragma unroll
  for (int m = 0; m < 4; ++m)
    #pragma unroll
    for (int n = 0; n < 4; ++n) acc[m][n] = zf;

  const unsigned short* gA = A  + (size_t)(mBase + (lane>>3)) * DIMC + (lane&7)*8;
  const unsigned short* gB = Bt + (size_t)(nBase + (lane>>3)) * DIMC + (lane&7)*8;

  for (int kt = 0; kt < 8; ++kt) {
    int k0 = kt * 64;
    if (kt) __syncthreads();
    #pragma unroll
    for (int r = 0; r < 4; ++r) {
      int row0 = r*32 + w*8;
      gload16(gA + (size_t)row0 * DIMC + k0, &As[row0][0]);
      gload16(gB + (size_t)row0 * DIMC + k0, &Bs[row0][0]);
    }
    __syncthreads();
    #pragma unroll
    for (int t = 0; t < 2; ++t) {
      s8v af[4], bfr[4];
      #pragma unroll
      for (int m = 0; m < 4; ++m)
        af[m] = *(const s8v*)&As[wr*64 + m*16 + (lane&15)][t*32 + (lane>>4)*8];
      #pragma unroll
      for (int n = 0; n < 4; ++n)
        bfr[n] = *(const s8v*)&Bs[wc*64 + n*16 + (lane&15)][t*32 + (lane>>4)*8];
      #pragma unroll
      for (int m = 0; m < 4; ++m)
        #pragma unroll
        for (int n = 0; n < 4; ++n)
          acc[m][n] = __builtin_amdgcn_mfma_f32_16x16x32_bf16(af[m], bfr[n], acc[m][n], 0, 0, 0);
    }
  }

  #pragma unroll
  for (int m = 0; m < 4; ++m) {
    int row = mBase + wr*64 + m*16 + (lane>>4)*4;
    #pragma unroll
    for (int n = 0; n < 4; ++n) {
      int col = nBase + wc*64 + n*16 + (lane&15);
      float bb = bo[col];
      #pragma unroll
      for (int j = 0; j < 4; ++j) {
        size_t idx = (size_t)(row+j)*DIMC + col;
        out[idx] = acc[m][n][j] + bb + resid[idx];
      }
    }
  }
}

// ---------------- Flash cross-attention --------------------------------
// 64 Q rows/block (4 waves x 16). KV tiles of 64, double-buffered LDS,
// counted vmcnt(4) + raw s_barrier so prefetch stays in flight (T3/T4).
// K: row-major global, source-XOR swizzle into Ks (R4-proven).
// V: permuted-transposed global, same swizzle; PV B-frag = single b128.
__global__ void attn_kernel(const unsigned short* __restrict__ Q, const unsigned short* __restrict__ K,
                            const unsigned short* __restrict__ Vt, unsigned short* __restrict__ O) {
  __shared__ __align__(16) char Ks[2][8192];   // [buf][64 key][64 d] swizzled
  __shared__ __align__(16) char Vs[2][8192];   // [buf][64 d][64 pos] swizzled

  int tid = threadIdx.x, w = tid >> 6, lane = tid & 63;
  int qb = blockIdx.x;          // 0..31
  int bh = blockIdx.y;          // 0..31
  int b = bh >> 3, h = bh & 7;
  size_t base  = ((size_t)b * NB) * DIMC + h * 64;        // Q/K row-major base
  size_t vbase = (size_t)(b*8 + h) * 64 * 2048;           // V^T base

  int g = lane >> 4;            // 0..3
  int l15 = lane & 15;

  int qrow = qb*64 + w*16 + l15;
  const s8v qf0 = *(const s8v*)&Q[base + (size_t)qrow*DIMC + g*8];
  const s8v qf1 = *(const s8v*)&Q[base + (size_t)qrow*DIMC + 32 + g*8];

  f4v zf = {0.f, 0.f, 0.f, 0.f};
  f4v o_[4];
  #pragma unroll
  for (int c = 0; c < 4; ++c) o_[c] = zf;
  float m_run = -1e30f, l_run = 0.f;

  // staging: per thread 2 K-rows + 2 V-rows, 16B each
  int sub = lane >> 3;                         // 0..7
  int grp = ((lane & 7) ^ sub) * 8;            // source-XOR column group
  const unsigned short* Kg = K + base;
  const unsigned short* Vg = Vt + vbase;
  int krow0 = w*16 + sub,  krow1 = w*16 + 8 + sub;
  unsigned sdst0 = (unsigned)(w*2048);
  unsigned sdst1 = (unsigned)(w*2048 + 1024);

  // per-lane read offsets (identical for Ks and Vs rows; c-step = +2048B)
  int sw = (l15 & 7) << 4;
  unsigned a0 = (unsigned)(l15*128 + ((16*g) ^ sw));
  unsigned a1 = (unsigned)(l15*128 + (((64 + 16*g)) ^ sw));

  // prologue: stage tile 0 into buf 0
  gload16(Kg + (size_t)(krow0)*DIMC + grp, Ks[0] + sdst0);
  gload16(Kg + (size_t)(krow1)*DIMC + grp, Ks[0] + sdst1);
  gload16(Vg + (size_t)(krow0)*2048 + grp, Vs[0] + sdst0);
  gload16(Vg + (size_t)(krow1)*2048 + grp, Vs[0] + sdst1);

  #pragma unroll 1
  for (int tt = 0; tt < 16; ++tt) {
    #pragma unroll
    for (int p = 0; p < 2; ++p) {
      int t = tt*2 + p;
      const char* KsB = Ks[p];
      const char* VsB = Vs[p];
      char* KsN = Ks[p^1];
      char* VsN = Vs[p^1];

      if (t < 31) {
        int kv = (t+1)*64;
        gload16(Kg + (size_t)(kv + krow0)*DIMC + grp, KsN + sdst0);
        gload16(Kg + (size_t)(kv + krow1)*DIMC + grp, KsN + sdst1);
        gload16(Vg + (size_t)(krow0)*2048 + kv + grp, VsN + sdst0);
        gload16(Vg + (size_t)(krow1)*2048 + kv + grp, VsN + sdst1);
        asm volatile("s_waitcnt vmcnt(4)" ::: "memory");
      } else {
        asm volatile("s_waitcnt vmcnt(0)" ::: "memory");
      }
      __builtin_amdgcn_s_barrier();
      __builtin_amdgcn_sched_barrier(0);

      // QK^T: st[c][j] = S[key=16c+4g+j][qrow]
      f4v st[4];
      #pragma unroll
      for (int c = 0; c < 4; ++c) {
        s8v ka = *(const s8v*)(KsB + c*2048 + a0);
        s8v kb = *(const s8v*)(KsB + c*2048 + a1);
        st[c] = __builtin_amdgcn_mfma_f32_16x16x32_bf16(ka, qf0, zf, 0, 0, 0);
        st[c] = __builtin_amdgcn_mfma_f32_16x16x32_bf16(kb, qf1, st[c], 0, 0, 0);
      }

      // PV B-fragments: single b128 each thanks to V key-permutation
      s8v vf0[4], vf1[4];
      #pragma unroll
      for (int c = 0; c < 4; ++c) {
        vf0[c] = *(const s8v*)(VsB + c*2048 + a0);
        vf1[c] = *(const s8v*)(VsB + c*2048 + a1);
      }

      // row max (per-lane row = l15, reduce across 4 lane-groups)
      float mx0 = fmaxf(fmaxf(st[0][0], st[0][1]), fmaxf(st[0][2], st[0][3]));
      float mx1 = fmaxf(fmaxf(st[1][0], st[1][1]), fmaxf(st[1][2], st[1][3]));
      float mx2 = fmaxf(fmaxf(st[2][0], st[2][1]), fmaxf(st[2][2], st[2][3]));
      float mx3 = fmaxf(fmaxf(st[3][0], st[3][1]), fmaxf(st[3][2], st[3][3]));
      float mt = fmaxf(fmaxf(mx0, mx1), fmaxf(mx2, mx3));
      mt = fmaxf(mt, __shfl_xor(mt, 16));
      mt = fmaxf(mt, __shfl_xor(mt, 32));

      // defer-max: only rescale when max grew by more than 8 (log2 units)
      if (!__all(mt <= m_run + 8.0f)) {
        float mn = fmaxf(m_run, mt);
        float f = __builtin_amdgcn_exp2f(m_run - mn);
        l_run *= f;
        m_run = mn;
        float fb0 = __shfl(f, g*4+0), fb1 = __shfl(f, g*4+1);
        float fb2 = __shfl(f, g*4+2), fb3 = __shfl(f, g*4+3);
        #pragma unroll
        for (int c = 0; c < 4; ++c) {
          o_[c][0] *= fb0; o_[c][1] *= fb1; o_[c][2] *= fb2; o_[c][3] *= fb3;
        }
      }

      float pt[4][4];
      #pragma unroll
      for (int c = 0; c < 4; ++c)
        #pragma unroll
        for (int j = 0; j < 4; ++j)
          pt[c][j] = __builtin_amdgcn_exp2f(st[c][j] - m_run);

      float s0 = (pt[0][0]+pt[0][1]) + (pt[0][2]+pt[0][3]);
      float s1 = (pt[1][0]+pt[1][1]) + (pt[1][2]+pt[1][3]);
      float s2 = (pt[2][0]+pt[2][1]) + (pt[2][2]+pt[2][3]);
      float s3 = (pt[3][0]+pt[3][1]) + (pt[3][2]+pt[3][3]);
      float ps = (s0+s1) + (s2+s3);
      ps += __shfl_xor(ps, 16);
      ps += __shfl_xor(ps, 32);
      l_run += ps;

      // pack P -> bf16 A-fragments (slot e -> key (e>>2)*16 + 4g + (e&3))
      union { unsigned i[8]; s8v s[2]; } pu;
      pu.i[0] = cvt_pk_bf16(pt[0][0], pt[0][1]);
      pu.i[1] = cvt_pk_bf16(pt[0][2], pt[0][3]);
      pu.i[2] = cvt_pk_bf16(pt[1][0], pt[1][1]);
      pu.i[3] = cvt_pk_bf16(pt[1][2], pt[1][3]);
      pu.i[4] = cvt_pk_bf16(pt[2][0], pt[2][1]);
      pu.i[5] = cvt_pk_bf16(pt[2][2], pt[2][3]);
      pu.i[6] = cvt_pk_bf16(pt[3][0], pt[3][1]);
      pu.i[7] = cvt_pk_bf16(pt[3][2], pt[3][3]);

      #pragma unroll
      for (int c = 0; c < 4; ++c) {
        o_[c] = __builtin_amdgcn_mfma_f32_16x16x32_bf16(pu.s[0], vf0[c], o_[c], 0, 0, 0);
        o_[c] = __builtin_amdgcn_mfma_f32_16x16x32_bf16(pu.s[1], vf1[c], o_[c], 0, 0, 0);
      }

      __builtin_amdgcn_sched_barrier(0);
      __builtin_amdgcn_s_barrier();
    }
  }

  // finalize: divide by row sum, store bf16
  float lb[4];
  #pragma unroll
  for (int j = 0; j < 4; ++j) lb[j] = 1.0f / __shfl(l_run, g*4 + j);
  int nrow = qb*64 + w*16 + g*4;
  #pragma unroll
  for (int c = 0; c < 4; ++c) {
    int d = h*64 + c*16 + l15;
    #pragma unroll
    for (int j = 0; j < 4; ++j)
      O[((size_t)b*NB + nrow + j) * DIMC + d] = cvt_bf16(o_[c][j] * lb[j]);
  }
}

// ---------------- launch --------------------------------------------------
extern "C" void kernel_launch(void* const* d_in, const int* in_sizes, int n_in,
                              void* d_out, int out_size, void* d_ws, size_t ws_size,
                              hipStream_t stream) {
  const float* x    = (const float*)d_in[0];
  const float* ctx  = (const float*)d_in[1];
  const float* g_q  = (const float*)d_in[2];
  const float* b_q  = (const float*)d_in[3];
  const float* g_kv = (const float*)d_in[4];
  const float* b_kv = (const float*)d_in[5];
  const float* Wq   = (const float*)d_in[6];
  const float* bq   = (const float*)d_in[7];
  const float* Wk   = (const float*)d_in[8];
  const float* bk   = (const float*)d_in[9];
  const float* Wv   = (const float*)d_in[10];
  const float* bv   = (const float*)d_in[11];
  const float* Wo   = (const float*)d_in[12];
  const float* bo   = (const float*)d_in[13];
  float* out = (float*)d_out;

  char* ws = (char*)d_ws;
  unsigned short* xn = (unsigned short*)(ws);                    //  8 MB
  unsigned short* cn = (unsigned short*)(ws + 8388608);          //  8 MB
  unsigned short* Wt = (unsigned short*)(ws + 16777216);         //  2 MB (4 matrices)
  unsigned short* Qb = (unsigned short*)(ws + 18874368);         //  8 MB
  unsigned short* Kb = (unsigned short*)(ws + 27262976);         //  8 MB
  unsigned short* Vb = (unsigned short*)(ws + 35651584);         //  8 MB (V^T, key-permuted)
  unsigned short* Ab = cn;  // attention output reuses cn (dead after QKV GEMM)

  ln_kernel<<<4096, 256, 0, stream>>>(x, ctx, g_q, b_q, g_kv, b_kv, xn, cn);
  wt_kernel<<<dim3(8, 8, 4), 256, 0, stream>>>(Wq, Wk, Wv, Wo, Wt);
  gemm_qkv<<<dim3(64, 4, 3), 256, 0, stream>>>(xn, cn, Wt, bq, bk, bv, Qb, Kb, Vb);
  attn_kernel<<<dim3(32, 32), 256, 0, stream>>>(Qb, Kb, Vb, Ab);
  gemm_out<<<dim3(64, 4), 256, 0, stream>>>(Ab, Wt + 3*DIMC*DIMC, bo, x, out);
}